// Round 4
// baseline (5718.129 us; speedup 1.0000x reference)
//
#include <hip/hip_runtime.h>
#include <hip/hip_bf16.h>
#include <math.h>

#define B_ 128
#define T_ 32
#define IN_ 512
#define H_ 512
#define M_ 16
#define WC_ 20
#define R_ 4
#define RW_ 80
#define NNIN_ 592
#define IFACE_ 163
#define IFP_ 176
#define K1P_ 1120
#define K2P_ 1024
#define KOP_ 608
#define CLIP_ 20.0f
#define EPS_ 1e-6f
#define DELTA_ 5e-6f
#define NBLK_ 1536

typedef __bf16 bf16x8 __attribute__((ext_vector_type(8)));
typedef float f32x4 __attribute__((ext_vector_type(4)));

__device__ __forceinline__ float sigmoidf_(float x) { return 1.0f / (1.0f + expf(-x)); }
__device__ __forceinline__ float softplusf_(float x) {
    return fmaxf(x, 0.0f) + log1pf(expf(-fabsf(x)));
}
__device__ __forceinline__ void split2(float v, __bf16* hp, __bf16* lp) {
    __bf16 h = (__bf16)v;
    *hp = h;
    *lp = (__bf16)(v - (float)h);
}

// ---------------------------------------------------------------------------
// Parameter block. LSTM/out weights: single bf16 limb. iface weights: 2-limb
// bf16 (hi+lo). Activations split hi/lo.
// ---------------------------------------------------------------------------
struct P {
    const float *x, *bih0, *bhh0, *bih1, *bhh1, *bif0, *bif1, *bout;
    float* out;
    __bf16 *a10h[4], *a10l[4];   // [x | 0 | h00], stride K1P
    __bf16 *a11h[4], *a11l[4];   // [out0 | rv0 | h10], stride K1P
    __bf16 *a20h[4], *a20l[4];   // [h0A | h01], stride K2P
    __bf16 *a21h[4], *a21l[4];   // [h1A | h11], stride K2P
    __bf16 *yh[4],  *yl[4];      // [out1 | rv1 | pad], stride KOP
    float *c00, *c01, *c10, *c11;
    float *mem0, *link0, *prec0, *rw0, *ww0, *us0;
    float *mem1, *link1, *prec1, *rw1, *ww1, *us1;
    __bf16 *w10, *w20, *w11, *w21, *wo;
    __bf16 *wif0h, *wif0l, *wif1h, *wif1l;   // [IFP_ x 512]
    float *S0[2], *S1[2];                    // [B_ x IFP_] activated iface
    unsigned *bar;                            // grid barrier state (zeroed)
};

// ---------------------------------------------------------------------------
// Hand-rolled grid barrier (normal launch; co-residency guaranteed by
// 1536 blocks = 6/CU with launch_bounds(256,6)).
// Layout in p.bar: [s*32] 32 shard counters (128B apart), [1024] root,
// [1040] generation. All zeroed by the per-call memset.
// Caller passes g = slot index; barrier releases by setting gen = g+1.
// ---------------------------------------------------------------------------
__device__ __forceinline__ void grid_barrier(unsigned* bar, int blk, int tid, unsigned g)
{
    __syncthreads();   // gfx950: drains vmcnt -> block's stores are in L2
    if (tid == 0) {
        __threadfence();   // agent-scope release (L2 writeback for cross-XCD)
        unsigned a = __hip_atomic_fetch_add(&bar[(blk & 31) * 32], 1u,
                        __ATOMIC_ACQ_REL, __HIP_MEMORY_SCOPE_AGENT);
        if (a == 47u) {
            unsigned r = __hip_atomic_fetch_add(&bar[1024], 1u,
                            __ATOMIC_ACQ_REL, __HIP_MEMORY_SCOPE_AGENT);
            if (r == 31u) {
                #pragma unroll
                for (int s2 = 0; s2 < 32; ++s2)
                    __hip_atomic_store(&bar[s2 * 32], 0u,
                        __ATOMIC_RELAXED, __HIP_MEMORY_SCOPE_AGENT);
                __hip_atomic_store(&bar[1024], 0u,
                    __ATOMIC_RELAXED, __HIP_MEMORY_SCOPE_AGENT);
                __hip_atomic_store(&bar[1040], g + 1u,
                    __ATOMIC_RELEASE, __HIP_MEMORY_SCOPE_AGENT);
            }
        }
        long long spins = 0;
        while (__hip_atomic_load(&bar[1040], __ATOMIC_RELAXED,
                                 __HIP_MEMORY_SCOPE_AGENT) <= g) {
            __builtin_amdgcn_s_sleep(2);
            if (++spins > (1LL << 19)) break;   // bounded failure, never hang
        }
        __threadfence();   // agent-scope acquire (invalidate L1 / stale L2)
    }
    __syncthreads();
}

// ---------------------------------------------------------------------------
// Fused LSTM GEMM tile: 16x16 (batch x hidden) of all 4 gates, 4 waves split
// K, LDS reduce, wave0 runs LSTM pointwise epilogue.
// ---------------------------------------------------------------------------
__device__ __forceinline__ void gemm_lstm_tile(
    int tid, int jt, int mt, float* red,
    const __bf16* Ah, const __bf16* Al, int KS,
    const __bf16* W, int nsteps,
    const float* b1, const float* b2, float* cst,
    __bf16* d1h, __bf16* d1l, int st1, int off1,
    __bf16* d2h, __bf16* d2l, int st2, int off2, int clip2)
{
    const int wave = tid >> 6, lane = tid & 63;
    const int l15 = lane & 15, quad = lane >> 4;
    const int j0 = jt * 16, m0 = mt * 16;

    f32x4 acc[4];
    #pragma unroll
    for (int g = 0; g < 4; ++g)
        #pragma unroll
        for (int i = 0; i < 4; ++i) acc[g][i] = 0.f;

    const int ks = (wave * nsteps) >> 2;
    const int ke = ((wave + 1) * nsteps) >> 2;

    size_t aoff = (size_t)(m0 + l15) * KS + ks * 32 + quad * 8;
    size_t woff[4];
    #pragma unroll
    for (int g = 0; g < 4; ++g)
        woff[g] = (size_t)(g * 512 + j0 + l15) * KS + ks * 32 + quad * 8;

    for (int s = ks; s < ke; ++s) {
        bf16x8 ah = *(const bf16x8*)(Ah + aoff);
        bf16x8 al = *(const bf16x8*)(Al + aoff);
        aoff += 32;
        #pragma unroll
        for (int g = 0; g < 4; ++g) {
            bf16x8 wh = *(const bf16x8*)(W + woff[g]);
            woff[g] += 32;
            acc[g] = __builtin_amdgcn_mfma_f32_16x16x32_bf16(ah, wh, acc[g], 0, 0, 0);
            acc[g] = __builtin_amdgcn_mfma_f32_16x16x32_bf16(al, wh, acc[g], 0, 0, 0);
        }
    }

    if (wave > 0) {
        #pragma unroll
        for (int g = 0; g < 4; ++g)
            #pragma unroll
            for (int r = 0; r < 4; ++r)
                red[((g * 4 + r) * 3 + (wave - 1)) * 64 + lane] = acc[g][r];
    }
    __syncthreads();
    if (wave == 0) {
        const int col = j0 + l15;
        float bg[4];
        #pragma unroll
        for (int g = 0; g < 4; ++g) bg[g] = b1[g * 512 + col] + b2[g * 512 + col];
        #pragma unroll
        for (int r = 0; r < 4; ++r) {
            const int m = m0 + quad * 4 + r;
            float gv[4];
            #pragma unroll
            for (int g = 0; g < 4; ++g) {
                int i = g * 4 + r;
                gv[g] = acc[g][r] + red[(i * 3 + 0) * 64 + lane] + red[(i * 3 + 1) * 64 + lane]
                      + red[(i * 3 + 2) * 64 + lane] + bg[g];
            }
            float cold = cst[m * H_ + col];
            float cn = sigmoidf_(gv[1]) * cold + sigmoidf_(gv[0]) * tanhf(gv[2]);
            cst[m * H_ + col] = cn;
            float h = sigmoidf_(gv[3]) * tanhf(cn);
            split2(h, &d1h[(size_t)m * st1 + off1 + col], &d1l[(size_t)m * st1 + off1 + col]);
            float h2 = clip2 ? fminf(fmaxf(h, -CLIP_), CLIP_) : h;
            split2(h2, &d2h[(size_t)m * st2 + off2 + col], &d2l[(size_t)m * st2 + off2 + col]);
        }
    }
    __syncthreads();   // red reused by multi-tile callers / next slot
}

// ---------------------------------------------------------------------------
// Plain GEMM tile (out projection), W single-limb
// ---------------------------------------------------------------------------
__device__ __forceinline__ void gemm_plain_tile(
    int tid, int nt, int mt, float* red,
    const __bf16* Ah, const __bf16* Al, int AS,
    const __bf16* W, int WS,
    int nsteps, const float* bias, float* C, int ldc)
{
    const int wave = tid >> 6, lane = tid & 63;
    const int l15 = lane & 15, quad = lane >> 4;
    const int n0 = nt * 16, m0 = mt * 16;

    f32x4 acc;
    #pragma unroll
    for (int i = 0; i < 4; ++i) acc[i] = 0.f;

    const int ks = (wave * nsteps) >> 2;
    const int ke = ((wave + 1) * nsteps) >> 2;

    size_t aoff = (size_t)(m0 + l15) * AS + ks * 32 + quad * 8;
    size_t woff = (size_t)(n0 + l15) * WS + ks * 32 + quad * 8;

    for (int s = ks; s < ke; ++s) {
        bf16x8 ah = *(const bf16x8*)(Ah + aoff);
        bf16x8 al = *(const bf16x8*)(Al + aoff);
        bf16x8 wh = *(const bf16x8*)(W + woff);
        aoff += 32; woff += 32;
        acc = __builtin_amdgcn_mfma_f32_16x16x32_bf16(ah, wh, acc, 0, 0, 0);
        acc = __builtin_amdgcn_mfma_f32_16x16x32_bf16(al, wh, acc, 0, 0, 0);
    }

    if (wave > 0) {
        #pragma unroll
        for (int r = 0; r < 4; ++r) red[(r * 3 + (wave - 1)) * 64 + lane] = acc[r];
    }
    __syncthreads();
    if (wave == 0) {
        const int col = n0 + l15;
        const float bc = bias[col];
        #pragma unroll
        for (int r = 0; r < 4; ++r) {
            const int m = m0 + quad * 4 + r;
            float v = acc[r] + red[(r * 3 + 0) * 64 + lane] + red[(r * 3 + 1) * 64 + lane]
                    + red[(r * 3 + 2) * 64 + lane] + bc;
            C[(size_t)m * ldc + col] = v;
        }
    }
    __syncthreads();
}

// ---------------------------------------------------------------------------
// iface GEMM tile: S = act(out @ Wif^T + bif). A 2-limb x W 2-limb, 3 MFMAs
// per K-step (al*wl dropped). K = 512 fixed -> 16 steps, 4 per wave.
// ---------------------------------------------------------------------------
__device__ __forceinline__ void gemm_iface_tile(
    int tid, int jt, int mt, float* red,
    const __bf16* Ah, const __bf16* Al, int AS,
    const __bf16* Wh, const __bf16* Wl,
    const float* bif, float* Sout)
{
    const int wave = tid >> 6, lane = tid & 63;
    const int l15 = lane & 15, quad = lane >> 4;
    const int n0 = jt * 16, m0 = mt * 16;

    f32x4 acc;
    #pragma unroll
    for (int i = 0; i < 4; ++i) acc[i] = 0.f;

    size_t aoff = (size_t)(m0 + l15) * AS + wave * 128 + quad * 8;
    size_t woff = (size_t)(n0 + l15) * 512 + wave * 128 + quad * 8;

    #pragma unroll
    for (int s = 0; s < 4; ++s) {
        bf16x8 ah = *(const bf16x8*)(Ah + aoff);
        bf16x8 al = *(const bf16x8*)(Al + aoff);
        bf16x8 wh = *(const bf16x8*)(Wh + woff);
        bf16x8 wl = *(const bf16x8*)(Wl + woff);
        aoff += 32; woff += 32;
        acc = __builtin_amdgcn_mfma_f32_16x16x32_bf16(ah, wh, acc, 0, 0, 0);
        acc = __builtin_amdgcn_mfma_f32_16x16x32_bf16(al, wh, acc, 0, 0, 0);
        acc = __builtin_amdgcn_mfma_f32_16x16x32_bf16(ah, wl, acc, 0, 0, 0);
    }

    if (wave > 0) {
        #pragma unroll
        for (int r = 0; r < 4; ++r) red[(r * 3 + (wave - 1)) * 64 + lane] = acc[r];
    }
    __syncthreads();
    if (wave == 0) {
        const int o = n0 + l15;
        const float bc = (o < IFACE_) ? bif[o] : 0.f;
        #pragma unroll
        for (int r = 0; r < 4; ++r) {
            const int m = m0 + quad * 4 + r;
            float v = acc[r] + red[(r * 3 + 0) * 64 + lane] + red[(r * 3 + 1) * 64 + lane]
                    + red[(r * 3 + 2) * 64 + lane] + bc;
            if (o < IFACE_) {
                float rr;
                if (o < 80)        rr = tanhf(v);
                else if (o < 84)   rr = softplusf_(v);
                else if (o < 104)  rr = tanhf(v);
                else if (o < 105)  rr = softplusf_(v);
                else if (o < 125)  rr = sigmoidf_(v);
                else if (o < 145)  rr = tanhf(v);
                else if (o < 151)  rr = sigmoidf_(v);
                else               rr = v;
                Sout[(size_t)m * IFP_ + o] = rr;
            }
        }
    }
    __syncthreads();
}

// ---------------------------------------------------------------------------
// DNC memory-step core (one block per batch element, 256 threads). S[0..162]
// holds the transformed iface vector on entry. 16-lane register reductions.
// ---------------------------------------------------------------------------
__device__ void mem_core(int b, int tid, float* S,
    float* mem, float* link, float* prec, float* rw,
    float* ww, float* usage, __bf16* rvh, __bf16* rvl, int rvst)
{
    float* sif     = S;
    float* modes   = S + 164;
    float* wwnewS  = S + 208;
    float* precold = S + 224;
    float* rwold   = S + 240;
    float* rwnewS  = S + 304;
    float* lnk     = S + 368;   // 256
    float* memS    = S + 624;   // 320

    if (tid < M_)       precold[tid] = prec[(size_t)b * M_ + tid];
    if (tid < R_ * M_)  rwold[tid]   = rw[(size_t)b * R_ * M_ + tid];
    if (tid < M_ * M_)  lnk[tid]     = link[(size_t)b * M_ * M_ + tid];
    for (int i = tid; i < M_ * WC_; i += 256) memS[i] = mem[(size_t)b * M_ * WC_ + i];
    if (tid < R_) {
        float a0 = sif[151 + tid * 3], a1 = sif[152 + tid * 3], a2 = sif[153 + tid * 3];
        float mx = fmaxf(a0, fmaxf(a1, a2));
        float e0 = expf(a0 - mx), e1 = expf(a1 - mx), e2 = expf(a2 - mx);
        float s = e0 + e1 + e2;
        modes[tid * 3 + 0] = e0 / s; modes[tid * 3 + 1] = e1 / s; modes[tid * 3 + 2] = e2 / s;
    }
    __syncthreads();

    if (tid < M_) {
        const int m = tid;
        float wwold = ww[(size_t)b * M_ + m];
        float u = usage[(size_t)b * M_ + m];
        u = u + (1.f - u) * wwold;
        float psi = 1.f;
        #pragma unroll
        for (int r = 0; r < R_; ++r) psi *= (1.f - sif[145 + r] * rwold[r * 16 + m]);
        u *= psi;

        float kn2 = 0.f, mn2 = 0.f, dot = 0.f;
        #pragma unroll
        for (int w = 0; w < WC_; ++w) {
            float kv = sif[84 + w], mv = memS[m * WC_ + w];
            kn2 += kv * kv; mn2 += mv * mv; dot += kv * mv;
        }
        float c = dot / ((sqrtf(kn2) + EPS_) * (sqrtf(mn2) + EPS_)) * sif[104];
        float mx = c;
        #pragma unroll
        for (int off = 8; off; off >>= 1) mx = fmaxf(mx, __shfl_xor(mx, off, 16));
        float e = expf(c - mx);
        float se = e;
        #pragma unroll
        for (int off = 8; off; off >>= 1) se += __shfl_xor(se, off, 16);
        float wcw = e / se;

        float uu = DELTA_ + (1.f - DELTA_) * u;
        int rank = 0;
        #pragma unroll
        for (int j = 0; j < 16; ++j) {
            float uj = __shfl(uu, j, 16);
            if (uj < uu || (uj == uu && j < m)) ++rank;
        }
        float prod = 1.f;
        #pragma unroll
        for (int j = 0; j < 16; ++j) {
            float uj = __shfl(uu, j, 16);
            int   rj = __shfl(rank, j, 16);
            if (rj < rank) prod *= uj;
        }
        float alloc = (1.f - uu) * prod;

        float ag = sif[149], wg = sif[150];
        float wwn = wg * (ag * alloc + (1.f - ag) * wcw);
        float sw = wwn;
        #pragma unroll
        for (int off = 8; off; off >>= 1) sw += __shfl_xor(sw, off, 16);

        wwnewS[m] = wwn;
        usage[(size_t)b * M_ + m] = u;
        ww[(size_t)b * M_ + m]    = wwn;
        prec[(size_t)b * M_ + m]  = (1.f - sw) * precold[m] + wwn;
    }
    __syncthreads();

    for (int i = tid; i < M_ * WC_; i += 256) {
        int m = i / WC_, w = i - m * WC_;
        float nm = memS[i] * (1.f - wwnewS[m] * sif[105 + w]) + wwnewS[m] * sif[125 + w];
        memS[i] = nm;
        mem[(size_t)b * M_ * WC_ + i] = nm;
    }
    if (tid < M_ * M_) {
        int i = tid >> 4, j = tid & 15;
        float v = (1.f - wwnewS[i] - wwnewS[j]) * lnk[tid] + wwnewS[i] * precold[j];
        if (i == j) v = 0.f;
        lnk[tid] = v;
        link[(size_t)b * M_ * M_ + tid] = v;
    }
    __syncthreads();

    if (tid < 64) {
        const int r = tid >> 4, m = tid & 15;
        float kn2 = 0.f, mn2 = 0.f, dot = 0.f;
        #pragma unroll
        for (int w = 0; w < WC_; ++w) {
            float kv = sif[r * WC_ + w], mv = memS[m * WC_ + w];
            kn2 += kv * kv; mn2 += mv * mv; dot += kv * mv;
        }
        float c = dot / ((sqrtf(kn2) + EPS_) * (sqrtf(mn2) + EPS_)) * sif[80 + r];
        float mx = c;
        #pragma unroll
        for (int off = 8; off; off >>= 1) mx = fmaxf(mx, __shfl_xor(mx, off, 16));
        float e = expf(c - mx);
        float se = e;
        #pragma unroll
        for (int off = 8; off; off >>= 1) se += __shfl_xor(se, off, 16);
        float rc = e / se;

        float fwd = 0.f, bwd = 0.f;
        #pragma unroll
        for (int j = 0; j < M_; ++j) fwd += lnk[m * 16 + j] * rwold[r * 16 + j];
        #pragma unroll
        for (int i2 = 0; i2 < M_; ++i2) bwd += rwold[r * 16 + i2] * lnk[i2 * 16 + m];
        float v = modes[r * 3 + 0] * bwd + modes[r * 3 + 1] * fwd + modes[r * 3 + 2] * rc;
        rwnewS[tid] = v;
        rw[(size_t)b * R_ * M_ + tid] = v;
    }
    __syncthreads();

    if (tid < RW_) {
        int r = tid / WC_, w = tid - r * WC_;
        float s = 0.f;
        #pragma unroll
        for (int m = 0; m < M_; ++m) s += rwnewS[r * 16 + m] * memS[m * WC_ + w];
        split2(s, &rvh[(size_t)b * rvst + IN_ + tid], &rvl[(size_t)b * rvst + IN_ + tid]);
    }
    __syncthreads();
}

__device__ void mem_group(int b, int tid, float* smem, const float* Sbuf,
    float* mem, float* link, float* prec, float* rw, float* ww, float* usage,
    __bf16* rvh, __bf16* rvl, int rvst)
{
    float* S = smem;
    for (int i = tid; i < IFACE_; i += 256) S[i] = Sbuf[(size_t)b * IFP_ + i];
    __syncthreads();
    mem_core(b, tid, S, mem, link, prec, rw, ww, usage, rvh, rvl, rvst);
}

// ---------------------------------------------------------------------------
// Persistent kernel (NORMAL launch, graph-capturable): all 40 pipeline slots
// in one dispatch; hand-rolled grid barrier between slots. 1536 blocks =
// 6 blocks/CU co-resident by construction. Per-slot stage map:
//   [0,256):      A0(t=s)
//   [256,512):    B0(t=s-1)
//   [512,768):    A1(t=s-4)
//   [768,1024):   B1(t=s-5)
//   [1024,1152):  M0(t=s-3)
//   [1152,1280):  M1(t=s-7)
//   [1280,1408):  Y(t=s-8)    128 blocks x 2 tiles
//   [1408,1452):  IF0(t=s-2)  44 blocks x 2 tiles
//   [1452,1496):  IF1(t=s-6)  44 blocks x 2 tiles
//   [1496,1528):  x(s+1) convert
//   [1528,1536):  idle (barrier participants)
// ---------------------------------------------------------------------------
__global__ __launch_bounds__(256, 6) void persist_kernel(P p)
{
    __shared__ float smem[3072];
    const int blk = blockIdx.x, tid = threadIdx.x;

    for (int s = 0; s < T_ + 8; ++s) {
        if (blk < 256) {                       // A0(t=s)
            int t = s;
            if (t < T_) {
                gemm_lstm_tile(tid, blk & 31, blk >> 5, smem,
                    p.a10h[t & 3], p.a10l[t & 3], K1P_, p.w10, K1P_ / 32,
                    p.bih0, p.bhh0, p.c00,
                    p.a10h[(t + 1) & 3], p.a10l[(t + 1) & 3], K1P_, NNIN_,
                    p.a20h[t & 3], p.a20l[t & 3], K2P_, 0, 0);
            }
        } else if (blk < 512) {                // B0(t=s-1)
            int t = s - 1;
            if (t >= 0 && t < T_) {
                int b2 = blk - 256;
                gemm_lstm_tile(tid, b2 & 31, b2 >> 5, smem,
                    p.a20h[t & 3], p.a20l[t & 3], K2P_, p.w20, K2P_ / 32,
                    p.bih1, p.bhh1, p.c01,
                    p.a20h[(t + 1) & 3], p.a20l[(t + 1) & 3], K2P_, H_,
                    p.a11h[t & 3], p.a11l[t & 3], K1P_, 0, 1);
            }
        } else if (blk < 768) {                // A1(t=s-4)
            int t = s - 4;
            if (t >= 0 && t < T_) {
                int b2 = blk - 512;
                gemm_lstm_tile(tid, b2 & 31, b2 >> 5, smem,
                    p.a11h[t & 3], p.a11l[t & 3], K1P_, p.w11, K1P_ / 32,
                    p.bih0 + 2048, p.bhh0 + 2048, p.c10,
                    p.a11h[(t + 1) & 3], p.a11l[(t + 1) & 3], K1P_, NNIN_,
                    p.a21h[t & 3], p.a21l[t & 3], K2P_, 0, 0);
            }
        } else if (blk < 1024) {               // B1(t=s-5)
            int t = s - 5;
            if (t >= 0 && t < T_) {
                int b2 = blk - 768;
                gemm_lstm_tile(tid, b2 & 31, b2 >> 5, smem,
                    p.a21h[t & 3], p.a21l[t & 3], K2P_, p.w21, K2P_ / 32,
                    p.bih1 + 2048, p.bhh1 + 2048, p.c11,
                    p.a21h[(t + 1) & 3], p.a21l[(t + 1) & 3], K2P_, H_,
                    p.yh[t & 3], p.yl[t & 3], KOP_, 0, 1);
            }
        } else if (blk < 1152) {               // M0(t=s-3)
            int t = s - 3;
            if (t >= 0 && t < T_) {
                mem_group(blk - 1024, tid, smem, p.S0[t & 1],
                    p.mem0, p.link0, p.prec0, p.rw0, p.ww0, p.us0,
                    p.a11h[t & 3], p.a11l[t & 3], K1P_);
            }
        } else if (blk < 1280) {               // M1(t=s-7)
            int t = s - 7;
            if (t >= 0 && t < T_) {
                mem_group(blk - 1152, tid, smem, p.S1[t & 1],
                    p.mem1, p.link1, p.prec1, p.rw1, p.ww1, p.us1,
                    p.yh[t & 3], p.yl[t & 3], KOP_);
            }
        } else if (blk < 1408) {               // Y(t=s-8), 2 tiles
            int t = s - 8;
            if (t >= 0 && t < T_) {
                int b2 = blk - 1280;
                gemm_plain_tile(tid, b2 & 31, b2 >> 5, smem,
                    p.yh[t & 3], p.yl[t & 3], KOP_, p.wo, KOP_, KOP_ / 32,
                    p.bout, p.out + (size_t)t * IN_, T_ * IN_);
                int tile = b2 + 128;
                gemm_plain_tile(tid, tile & 31, tile >> 5, smem,
                    p.yh[t & 3], p.yl[t & 3], KOP_, p.wo, KOP_, KOP_ / 32,
                    p.bout, p.out + (size_t)t * IN_, T_ * IN_);
            }
        } else if (blk < 1452) {               // IF0(t=s-2), 2 tiles
            int t = s - 2;
            if (t >= 0 && t < T_) {
                int b2 = blk - 1408;
                gemm_iface_tile(tid, b2 % 11, b2 / 11, smem,
                    p.a11h[t & 3], p.a11l[t & 3], K1P_,
                    p.wif0h, p.wif0l, p.bif0, p.S0[t & 1]);
                int tile = b2 + 44;
                gemm_iface_tile(tid, tile % 11, tile / 11, smem,
                    p.a11h[t & 3], p.a11l[t & 3], K1P_,
                    p.wif0h, p.wif0l, p.bif0, p.S0[t & 1]);
            }
        } else if (blk < 1496) {               // IF1(t=s-6), 2 tiles
            int t = s - 6;
            if (t >= 0 && t < T_) {
                int b2 = blk - 1452;
                gemm_iface_tile(tid, b2 % 11, b2 / 11, smem,
                    p.yh[t & 3], p.yl[t & 3], KOP_,
                    p.wif1h, p.wif1l, p.bif1, p.S1[t & 1]);
                int tile = b2 + 44;
                gemm_iface_tile(tid, tile % 11, tile / 11, smem,
                    p.yh[t & 3], p.yl[t & 3], KOP_,
                    p.wif1h, p.wif1l, p.bif1, p.S1[t & 1]);
            }
        } else if (blk < 1528) {               // x(s+1) convert
            int tn = s + 1;
            if (tn < T_) {
                for (int i = (blk - 1496) * 256 + tid; i < B_ * IN_; i += 32 * 256) {
                    int b = i >> 9, j = i & 511;
                    float v = p.x[((size_t)b * T_ + tn) * IN_ + j];
                    split2(v, &p.a10h[tn & 3][(size_t)b * K1P_ + j],
                              &p.a10l[tn & 3][(size_t)b * K1P_ + j]);
                }
            }
        }
        if (s != T_ + 7) grid_barrier(p.bar, blk, tid, (unsigned)s);
    }
}

// ---------------------------------------------------------------------------
// Setup kernels
// ---------------------------------------------------------------------------
__global__ __launch_bounds__(256) void conv_hi(
    const float* __restrict__ s1, int K1, const float* __restrict__ s2, int K2,
    int Nsrc, __bf16* __restrict__ hi, int Kd)
{
    int k = blockIdx.x * 256 + threadIdx.x;
    int n = blockIdx.y;
    if (k >= Kd) return;
    float v = 0.f;
    if (n < Nsrc) {
        if (k < K1) v = s1[(size_t)n * K1 + k];
        else if (k < K1 + K2) v = s2[(size_t)n * K2 + (k - K1)];
    }
    hi[(size_t)n * Kd + k] = (__bf16)v;
}

__global__ __launch_bounds__(256) void conv_hl(
    const float* __restrict__ src, int Nsrc, int K,
    __bf16* __restrict__ hi, __bf16* __restrict__ lo)
{
    int k = blockIdx.x * 256 + threadIdx.x;
    int n = blockIdx.y;
    if (k >= K) return;
    float v = (n < Nsrc) ? src[(size_t)n * K + k] : 0.f;
    split2(v, &hi[(size_t)n * K + k], &lo[(size_t)n * K + k]);
}

__global__ __launch_bounds__(256) void build_inp(const float* __restrict__ x,
                                                 __bf16* __restrict__ a1h,
                                                 __bf16* __restrict__ a1l)
{
    int idx = blockIdx.x * 256 + threadIdx.x;
    if (idx >= B_ * IN_) return;
    int b = idx >> 9, j = idx & 511;
    float v = x[(size_t)b * T_ * IN_ + j];
    split2(v, &a1h[b * K1P_ + j], &a1l[b * K1P_ + j]);
}

// ---------------------------------------------------------------------------
extern "C" void kernel_launch(void* const* d_in, const int* in_sizes, int n_in,
                              void* d_out, int out_size, void* d_ws, size_t ws_size,
                              hipStream_t stream)
{
    const float* x       = (const float*)d_in[0];
    const float* W_ih0   = (const float*)d_in[1];
    const float* W_hh0   = (const float*)d_in[2];
    const float* b_ih0   = (const float*)d_in[3];
    const float* b_hh0   = (const float*)d_in[4];
    const float* W_ih1   = (const float*)d_in[5];
    const float* W_hh1   = (const float*)d_in[6];
    const float* b_ih1   = (const float*)d_in[7];
    const float* b_hh1   = (const float*)d_in[8];
    const float* W_iface = (const float*)d_in[9];
    const float* b_iface = (const float*)d_in[10];
    const float* W_out   = (const float*)d_in[11];
    const float* b_out   = (const float*)d_in[12];

    P p;
    p.x = x;
    p.bih0 = b_ih0; p.bhh0 = b_hh0; p.bih1 = b_ih1; p.bhh1 = b_hh1;
    p.bif0 = b_iface; p.bif1 = b_iface + IFACE_;
    p.bout = b_out;
    p.out = (float*)d_out;

    char* ptr = (char*)d_ws;
    auto alloc = [&](size_t bytes) { char* r = ptr; ptr += (bytes + 255) & ~(size_t)255; return r; };

    // ---- zero zone (memset each call) ----
    char* zstart = ptr;
    for (int q = 0; q < 4; ++q) { p.a10h[q] = (__bf16*)alloc(B_ * K1P_ * 2); p.a10l[q] = (__bf16*)alloc(B_ * K1P_ * 2); }
    for (int q = 0; q < 4; ++q) { p.a11h[q] = (__bf16*)alloc(B_ * K1P_ * 2); p.a11l[q] = (__bf16*)alloc(B_ * K1P_ * 2); }
    for (int q = 0; q < 4; ++q) { p.a20h[q] = (__bf16*)alloc(B_ * K2P_ * 2); p.a20l[q] = (__bf16*)alloc(B_ * K2P_ * 2); }
    for (int q = 0; q < 4; ++q) { p.a21h[q] = (__bf16*)alloc(B_ * K2P_ * 2); p.a21l[q] = (__bf16*)alloc(B_ * K2P_ * 2); }
    for (int q = 0; q < 4; ++q) { p.yh[q]  = (__bf16*)alloc(B_ * KOP_ * 2);  p.yl[q]  = (__bf16*)alloc(B_ * KOP_ * 2); }
    p.c00 = (float*)alloc((size_t)B_ * H_ * 4);
    p.c01 = (float*)alloc((size_t)B_ * H_ * 4);
    p.c10 = (float*)alloc((size_t)B_ * H_ * 4);
    p.c11 = (float*)alloc((size_t)B_ * H_ * 4);
    p.mem0  = (float*)alloc((size_t)B_ * M_ * WC_ * 4);
    p.link0 = (float*)alloc((size_t)B_ * M_ * M_ * 4);
    p.prec0 = (float*)alloc((size_t)B_ * M_ * 4);
    p.rw0   = (float*)alloc((size_t)B_ * R_ * M_ * 4);
    p.ww0   = (float*)alloc((size_t)B_ * M_ * 4);
    p.us0   = (float*)alloc((size_t)B_ * M_ * 4);
    p.mem1  = (float*)alloc((size_t)B_ * M_ * WC_ * 4);
    p.link1 = (float*)alloc((size_t)B_ * M_ * M_ * 4);
    p.prec1 = (float*)alloc((size_t)B_ * M_ * 4);
    p.rw1   = (float*)alloc((size_t)B_ * R_ * M_ * 4);
    p.ww1   = (float*)alloc((size_t)B_ * M_ * 4);
    p.us1   = (float*)alloc((size_t)B_ * M_ * 4);
    p.bar   = (unsigned*)alloc(8192);
    size_t zbytes = (size_t)(ptr - zstart);

    // ---- weights (rewritten every call) ----
    p.w10 = (__bf16*)alloc(2048ull * K1P_ * 2);
    p.w11 = (__bf16*)alloc(2048ull * K1P_ * 2);
    p.w20 = (__bf16*)alloc(2048ull * K2P_ * 2);
    p.w21 = (__bf16*)alloc(2048ull * K2P_ * 2);
    p.wo  = (__bf16*)alloc(512ull * KOP_ * 2);
    p.wif0h = (__bf16*)alloc((size_t)IFP_ * 512 * 2);
    p.wif0l = (__bf16*)alloc((size_t)IFP_ * 512 * 2);
    p.wif1h = (__bf16*)alloc((size_t)IFP_ * 512 * 2);
    p.wif1l = (__bf16*)alloc((size_t)IFP_ * 512 * 2);
    for (int q = 0; q < 2; ++q) p.S0[q] = (float*)alloc((size_t)B_ * IFP_ * 4);
    for (int q = 0; q < 2; ++q) p.S1[q] = (float*)alloc((size_t)B_ * IFP_ * 4);

    hipMemsetAsync(zstart, 0, zbytes, stream);

    conv_hi<<<dim3((K1P_ + 255) / 256, 2048), 256, 0, stream>>>(
        W_ih0, NNIN_, W_hh0, H_, 2048, p.w10, K1P_);
    conv_hi<<<dim3((K1P_ + 255) / 256, 2048), 256, 0, stream>>>(
        W_ih0 + 2048ull * NNIN_, NNIN_, W_hh0 + 2048ull * H_, H_, 2048, p.w11, K1P_);
    conv_hi<<<dim3((K2P_ + 255) / 256, 2048), 256, 0, stream>>>(
        W_ih1, H_, W_hh1, H_, 2048, p.w20, K2P_);
    conv_hi<<<dim3((K2P_ + 255) / 256, 2048), 256, 0, stream>>>(
        W_ih1 + 2048ull * H_, H_, W_hh1 + 2048ull * H_, H_, 2048, p.w21, K2P_);
    conv_hi<<<dim3((KOP_ + 255) / 256, 512), 256, 0, stream>>>(
        W_out, NNIN_, nullptr, 0, 512, p.wo, KOP_);
    conv_hl<<<dim3(2, IFP_), 256, 0, stream>>>(
        W_iface, IFACE_, 512, p.wif0h, p.wif0l);
    conv_hl<<<dim3(2, IFP_), 256, 0, stream>>>(
        W_iface + (size_t)IFACE_ * 512, IFACE_, 512, p.wif1h, p.wif1l);
    build_inp<<<(B_ * IN_ + 255) / 256, 256, 0, stream>>>(x, p.a10h[0], p.a10l[0]);

    // single persistent launch: 40 slots with hand-rolled grid barriers
    persist_kernel<<<NBLK_, 256, 0, stream>>>(p);
}

// Round 5
// 978.549 us; speedup vs baseline: 5.8435x; 5.8435x over previous
//
#include <hip/hip_runtime.h>
#include <hip/hip_bf16.h>
#include <math.h>

#define B_ 128
#define T_ 32
#define IN_ 512
#define H_ 512
#define M_ 16
#define WC_ 20
#define R_ 4
#define RW_ 80
#define NNIN_ 592
#define IFACE_ 163
#define IFP_ 176
#define K1P_ 1120
#define K2P_ 1024
#define KOP_ 608
#define CLIP_ 20.0f
#define EPS_ 1e-6f
#define DELTA_ 5e-6f

typedef __bf16 bf16x8 __attribute__((ext_vector_type(8)));
typedef float f32x4 __attribute__((ext_vector_type(4)));

__device__ __forceinline__ float sigmoidf_(float x) { return 1.0f / (1.0f + __expf(-x)); }
__device__ __forceinline__ float tanhf_(float x) {
    float e = __expf(-2.f * fabsf(x));
    float t = (1.f - e) / (1.f + e);
    return copysignf(t, x);
}
__device__ __forceinline__ float softplusf_(float x) {
    return fmaxf(x, 0.0f) + log1pf(__expf(-fabsf(x)));
}
__device__ __forceinline__ void split2(float v, __bf16* hp, __bf16* lp) {
    __bf16 h = (__bf16)v;
    *hp = h;
    *lp = (__bf16)(v - (float)h);
}

// ---------------------------------------------------------------------------
// Parameter block. LSTM/out weights: single bf16 limb. iface weights: 2-limb
// bf16 (hi+lo). Activations split hi/lo.
// ---------------------------------------------------------------------------
struct P {
    const float *x, *bih0, *bhh0, *bih1, *bhh1, *bif0, *bif1, *bout;
    float* out;
    __bf16 *a10h[4], *a10l[4];   // [x | 0 | h00], stride K1P
    __bf16 *a11h[4], *a11l[4];   // [out0 | rv0 | h10], stride K1P
    __bf16 *a20h[4], *a20l[4];   // [h0A | h01], stride K2P
    __bf16 *a21h[4], *a21l[4];   // [h1A | h11], stride K2P
    __bf16 *yh[4],  *yl[4];      // [out1 | rv1 | pad], stride KOP
    float *c00, *c01, *c10, *c11;
    float *mem0, *link0, *prec0, *rw0, *ww0, *us0;
    float *mem1, *link1, *prec1, *rw1, *ww1, *us1;
    __bf16 *w10, *w20, *w11, *w21, *wo;
    __bf16 *wif0h, *wif0l, *wif1h, *wif1l;   // [IFP_ x 512]
    float *S0[2], *S1[2];                    // [B_ x IFP_] activated iface
};

// ---------------------------------------------------------------------------
// Fused LSTM GEMM tile: 16x16 (batch x hidden) of all 4 gates, 4 waves split
// K. All-wave LDS reduce; wave w runs the LSTM pointwise epilogue for row
// subset r=w (parallel transcendentals, parallel stores).
// red needs 16*256 floats (16 KB).
// ---------------------------------------------------------------------------
__device__ __forceinline__ void gemm_lstm_tile(
    int tid, int jt, int mt, float* red,
    const __bf16* Ah, const __bf16* Al, int KS,
    const __bf16* W, int nsteps,
    const float* b1, const float* b2, float* cst,
    __bf16* d1h, __bf16* d1l, int st1, int off1,
    __bf16* d2h, __bf16* d2l, int st2, int off2, int clip2)
{
    const int wave = tid >> 6, lane = tid & 63;
    const int l15 = lane & 15, quad = lane >> 4;
    const int j0 = jt * 16, m0 = mt * 16;

    f32x4 acc[4];
    #pragma unroll
    for (int g = 0; g < 4; ++g)
        #pragma unroll
        for (int i = 0; i < 4; ++i) acc[g][i] = 0.f;

    const int ks = (wave * nsteps) >> 2;
    const int ke = ((wave + 1) * nsteps) >> 2;

    size_t aoff = (size_t)(m0 + l15) * KS + ks * 32 + quad * 8;
    size_t woff[4];
    #pragma unroll
    for (int g = 0; g < 4; ++g)
        woff[g] = (size_t)(g * 512 + j0 + l15) * KS + ks * 32 + quad * 8;

    for (int s = ks; s < ke; ++s) {
        bf16x8 ah = *(const bf16x8*)(Ah + aoff);
        bf16x8 al = *(const bf16x8*)(Al + aoff);
        aoff += 32;
        #pragma unroll
        for (int g = 0; g < 4; ++g) {
            bf16x8 wh = *(const bf16x8*)(W + woff[g]);
            woff[g] += 32;
            acc[g] = __builtin_amdgcn_mfma_f32_16x16x32_bf16(ah, wh, acc[g], 0, 0, 0);
            acc[g] = __builtin_amdgcn_mfma_f32_16x16x32_bf16(al, wh, acc[g], 0, 0, 0);
        }
    }

    #pragma unroll
    for (int g = 0; g < 4; ++g)
        #pragma unroll
        for (int r = 0; r < 4; ++r)
            red[(g * 4 + r) * 256 + wave * 64 + lane] = acc[g][r];
    __syncthreads();

    // wave w handles rows m0 + quad*4 + w
    const int col = j0 + l15;
    const int m = m0 + quad * 4 + wave;
    float gv[4];
    #pragma unroll
    for (int g = 0; g < 4; ++g) {
        const float* rg = red + (g * 4 + wave) * 256;
        gv[g] = rg[lane] + rg[64 + lane] + rg[128 + lane] + rg[192 + lane]
              + b1[g * 512 + col] + b2[g * 512 + col];
    }
    float cold = cst[m * H_ + col];
    float cn = sigmoidf_(gv[1]) * cold + sigmoidf_(gv[0]) * tanhf_(gv[2]);
    cst[m * H_ + col] = cn;
    float h = sigmoidf_(gv[3]) * tanhf_(cn);
    split2(h, &d1h[(size_t)m * st1 + off1 + col], &d1l[(size_t)m * st1 + off1 + col]);
    float h2 = clip2 ? fminf(fmaxf(h, -CLIP_), CLIP_) : h;
    split2(h2, &d2h[(size_t)m * st2 + off2 + col], &d2l[(size_t)m * st2 + off2 + col]);
}

// ---------------------------------------------------------------------------
// Plain GEMM tile (out projection), W single-limb, all-wave epilogue.
// ---------------------------------------------------------------------------
__device__ __forceinline__ void gemm_plain_tile(
    int tid, int nt, int mt, float* red,
    const __bf16* Ah, const __bf16* Al, int AS,
    const __bf16* W, int WS,
    int nsteps, const float* bias, float* C, int ldc)
{
    const int wave = tid >> 6, lane = tid & 63;
    const int l15 = lane & 15, quad = lane >> 4;
    const int n0 = nt * 16, m0 = mt * 16;

    f32x4 acc;
    #pragma unroll
    for (int i = 0; i < 4; ++i) acc[i] = 0.f;

    const int ks = (wave * nsteps) >> 2;
    const int ke = ((wave + 1) * nsteps) >> 2;

    size_t aoff = (size_t)(m0 + l15) * AS + ks * 32 + quad * 8;
    size_t woff = (size_t)(n0 + l15) * WS + ks * 32 + quad * 8;

    for (int s = ks; s < ke; ++s) {
        bf16x8 ah = *(const bf16x8*)(Ah + aoff);
        bf16x8 al = *(const bf16x8*)(Al + aoff);
        bf16x8 wh = *(const bf16x8*)(W + woff);
        aoff += 32; woff += 32;
        acc = __builtin_amdgcn_mfma_f32_16x16x32_bf16(ah, wh, acc, 0, 0, 0);
        acc = __builtin_amdgcn_mfma_f32_16x16x32_bf16(al, wh, acc, 0, 0, 0);
    }

    #pragma unroll
    for (int r = 0; r < 4; ++r) red[r * 256 + wave * 64 + lane] = acc[r];
    __syncthreads();

    const int col = n0 + l15;
    const int m = m0 + quad * 4 + wave;
    const float* rg = red + wave * 256;
    float v = rg[lane] + rg[64 + lane] + rg[128 + lane] + rg[192 + lane] + bias[col];
    C[(size_t)m * ldc + col] = v;
}

// ---------------------------------------------------------------------------
// iface GEMM tile: S = act(out @ Wif^T + bif). A 2-limb x W 2-limb, 3 MFMAs
// per K-step (al*wl dropped). K = 512 fixed -> 16 steps, 4 per wave.
// All-wave epilogue.
// ---------------------------------------------------------------------------
__device__ __forceinline__ void gemm_iface_tile(
    int tid, int jt, int mt, float* red,
    const __bf16* Ah, const __bf16* Al, int AS,
    const __bf16* Wh, const __bf16* Wl,
    const float* bif, float* Sout)
{
    const int wave = tid >> 6, lane = tid & 63;
    const int l15 = lane & 15, quad = lane >> 4;
    const int n0 = jt * 16, m0 = mt * 16;

    f32x4 acc;
    #pragma unroll
    for (int i = 0; i < 4; ++i) acc[i] = 0.f;

    size_t aoff = (size_t)(m0 + l15) * AS + wave * 128 + quad * 8;
    size_t woff = (size_t)(n0 + l15) * 512 + wave * 128 + quad * 8;

    #pragma unroll
    for (int s = 0; s < 4; ++s) {
        bf16x8 ah = *(const bf16x8*)(Ah + aoff);
        bf16x8 al = *(const bf16x8*)(Al + aoff);
        bf16x8 wh = *(const bf16x8*)(Wh + woff);
        bf16x8 wl = *(const bf16x8*)(Wl + woff);
        aoff += 32; woff += 32;
        acc = __builtin_amdgcn_mfma_f32_16x16x32_bf16(ah, wh, acc, 0, 0, 0);
        acc = __builtin_amdgcn_mfma_f32_16x16x32_bf16(al, wh, acc, 0, 0, 0);
        acc = __builtin_amdgcn_mfma_f32_16x16x32_bf16(ah, wl, acc, 0, 0, 0);
    }

    #pragma unroll
    for (int r = 0; r < 4; ++r) red[r * 256 + wave * 64 + lane] = acc[r];
    __syncthreads();

    const int o = n0 + l15;
    if (o < IFACE_) {
        const int m = m0 + quad * 4 + wave;
        const float* rg = red + wave * 256;
        float v = rg[lane] + rg[64 + lane] + rg[128 + lane] + rg[192 + lane] + bif[o];
        float rr;
        if (o < 80)        rr = tanhf_(v);
        else if (o < 84)   rr = softplusf_(v);
        else if (o < 104)  rr = tanhf_(v);
        else if (o < 105)  rr = softplusf_(v);
        else if (o < 125)  rr = sigmoidf_(v);
        else if (o < 145)  rr = tanhf_(v);
        else if (o < 151)  rr = sigmoidf_(v);
        else               rr = v;
        Sout[(size_t)m * IFP_ + o] = rr;
    }
}

// ---------------------------------------------------------------------------
// DNC memory-step core (one block per batch element, 256 threads). S[0..162]
// holds the transformed iface vector on entry. 16-lane register reductions
// (shfl_xor softmax; rank-based alloc == stable argsort + excl. cumprod).
// ---------------------------------------------------------------------------
__device__ void mem_core(int b, int tid, float* S,
    float* mem, float* link, float* prec, float* rw,
    float* ww, float* usage, __bf16* rvh, __bf16* rvl, int rvst)
{
    float* sif     = S;
    float* modes   = S + 164;
    float* wwnewS  = S + 208;
    float* precold = S + 224;
    float* rwold   = S + 240;
    float* rwnewS  = S + 304;
    float* lnk     = S + 368;   // 256
    float* memS    = S + 624;   // 320

    if (tid < M_)       precold[tid] = prec[(size_t)b * M_ + tid];
    if (tid < R_ * M_)  rwold[tid]   = rw[(size_t)b * R_ * M_ + tid];
    if (tid < M_ * M_)  lnk[tid]     = link[(size_t)b * M_ * M_ + tid];
    for (int i = tid; i < M_ * WC_; i += 256) memS[i] = mem[(size_t)b * M_ * WC_ + i];
    if (tid < R_) {
        float a0 = sif[151 + tid * 3], a1 = sif[152 + tid * 3], a2 = sif[153 + tid * 3];
        float mx = fmaxf(a0, fmaxf(a1, a2));
        float e0 = __expf(a0 - mx), e1 = __expf(a1 - mx), e2 = __expf(a2 - mx);
        float s = e0 + e1 + e2;
        modes[tid * 3 + 0] = e0 / s; modes[tid * 3 + 1] = e1 / s; modes[tid * 3 + 2] = e2 / s;
    }
    __syncthreads();

    if (tid < M_) {
        const int m = tid;
        float wwold = ww[(size_t)b * M_ + m];
        float u = usage[(size_t)b * M_ + m];
        u = u + (1.f - u) * wwold;
        float psi = 1.f;
        #pragma unroll
        for (int r = 0; r < R_; ++r) psi *= (1.f - sif[145 + r] * rwold[r * 16 + m]);
        u *= psi;

        float kn2 = 0.f, mn2 = 0.f, dot = 0.f;
        #pragma unroll
        for (int w = 0; w < WC_; ++w) {
            float kv = sif[84 + w], mv = memS[m * WC_ + w];
            kn2 += kv * kv; mn2 += mv * mv; dot += kv * mv;
        }
        float c = dot / ((sqrtf(kn2) + EPS_) * (sqrtf(mn2) + EPS_)) * sif[104];
        float mx = c;
        #pragma unroll
        for (int off = 8; off; off >>= 1) mx = fmaxf(mx, __shfl_xor(mx, off, 16));
        float e = __expf(c - mx);
        float se = e;
        #pragma unroll
        for (int off = 8; off; off >>= 1) se += __shfl_xor(se, off, 16);
        float wcw = e / se;

        float uu = DELTA_ + (1.f - DELTA_) * u;
        int rank = 0;
        #pragma unroll
        for (int j = 0; j < 16; ++j) {
            float uj = __shfl(uu, j, 16);
            if (uj < uu || (uj == uu && j < m)) ++rank;
        }
        float prod = 1.f;
        #pragma unroll
        for (int j = 0; j < 16; ++j) {
            float uj = __shfl(uu, j, 16);
            int   rj = __shfl(rank, j, 16);
            if (rj < rank) prod *= uj;
        }
        float alloc = (1.f - uu) * prod;

        float ag = sif[149], wg = sif[150];
        float wwn = wg * (ag * alloc + (1.f - ag) * wcw);
        float sw = wwn;
        #pragma unroll
        for (int off = 8; off; off >>= 1) sw += __shfl_xor(sw, off, 16);

        wwnewS[m] = wwn;
        usage[(size_t)b * M_ + m] = u;
        ww[(size_t)b * M_ + m]    = wwn;
        prec[(size_t)b * M_ + m]  = (1.f - sw) * precold[m] + wwn;
    }
    __syncthreads();

    for (int i = tid; i < M_ * WC_; i += 256) {
        int m = i / WC_, w = i - m * WC_;
        float nm = memS[i] * (1.f - wwnewS[m] * sif[105 + w]) + wwnewS[m] * sif[125 + w];
        memS[i] = nm;
        mem[(size_t)b * M_ * WC_ + i] = nm;
    }
    if (tid < M_ * M_) {
        int i = tid >> 4, j = tid & 15;
        float v = (1.f - wwnewS[i] - wwnewS[j]) * lnk[tid] + wwnewS[i] * precold[j];
        if (i == j) v = 0.f;
        lnk[tid] = v;
        link[(size_t)b * M_ * M_ + tid] = v;
    }
    __syncthreads();

    if (tid < 64) {
        const int r = tid >> 4, m = tid & 15;
        float kn2 = 0.f, mn2 = 0.f, dot = 0.f;
        #pragma unroll
        for (int w = 0; w < WC_; ++w) {
            float kv = sif[r * WC_ + w], mv = memS[m * WC_ + w];
            kn2 += kv * kv; mn2 += mv * mv; dot += kv * mv;
        }
        float c = dot / ((sqrtf(kn2) + EPS_) * (sqrtf(mn2) + EPS_)) * sif[80 + r];
        float mx = c;
        #pragma unroll
        for (int off = 8; off; off >>= 1) mx = fmaxf(mx, __shfl_xor(mx, off, 16));
        float e = __expf(c - mx);
        float se = e;
        #pragma unroll
        for (int off = 8; off; off >>= 1) se += __shfl_xor(se, off, 16);
        float rc = e / se;

        float fwd = 0.f, bwd = 0.f;
        #pragma unroll
        for (int j = 0; j < M_; ++j) fwd += lnk[m * 16 + j] * rwold[r * 16 + j];
        #pragma unroll
        for (int i2 = 0; i2 < M_; ++i2) bwd += rwold[r * 16 + i2] * lnk[i2 * 16 + m];
        float v = modes[r * 3 + 0] * bwd + modes[r * 3 + 1] * fwd + modes[r * 3 + 2] * rc;
        rwnewS[tid] = v;
        rw[(size_t)b * R_ * M_ + tid] = v;
    }
    __syncthreads();

    if (tid < RW_) {
        int r = tid / WC_, w = tid - r * WC_;
        float s = 0.f;
        #pragma unroll
        for (int m = 0; m < M_; ++m) s += rwnewS[r * 16 + m] * memS[m * WC_ + w];
        split2(s, &rvh[(size_t)b * rvst + IN_ + tid], &rvl[(size_t)b * rvst + IN_ + tid]);
    }
}

// ---------------------------------------------------------------------------
// mem stage: load precomputed activated iface row (from IF stage) + mem core.
// ---------------------------------------------------------------------------
__device__ void mem_group(int b, int tid, float* smem, const float* Sbuf,
    float* mem, float* link, float* prec, float* rw, float* ww, float* usage,
    __bf16* rvh, __bf16* rvl, int rvst)
{
    float* S = smem;
    for (int i = tid; i < IFACE_; i += 256) S[i] = Sbuf[(size_t)b * IFP_ + i];
    __syncthreads();
    mem_core(b, tid, S, mem, link, prec, rw, ww, usage, rvh, rvl, rvst);
}

// ---------------------------------------------------------------------------
// One pipeline slot: 9 stages + x-prefetch (1744 blocks).
//   [0,256):      A0(t=s)
//   [256,512):    B0(t=s-1)
//   [512,768):    A1(t=s-4)
//   [768,1024):   B1(t=s-5)
//   [1024,1152):  M0(t=s-3)
//   [1152,1280):  M1(t=s-7)
//   [1280,1536):  Y(t=s-8)
//   [1536,1624):  IF0(t=s-2)
//   [1624,1712):  IF1(t=s-6)
//   [1712,1744):  x(s+1) convert
// launch_bounds(256,8): cap VGPR at 64 -> 8 blocks/CU resident.
// ---------------------------------------------------------------------------
__global__ __launch_bounds__(256, 8) void slot_kernel(P p, int s)
{
    __shared__ float smem[4096];
    const int blk = blockIdx.x, tid = threadIdx.x;

    if (blk < 256) {                       // A0(t=s)
        int t = s;
        if (t < T_) {
            gemm_lstm_tile(tid, blk & 31, blk >> 5, smem,
                p.a10h[t & 3], p.a10l[t & 3], K1P_, p.w10, K1P_ / 32,
                p.bih0, p.bhh0, p.c00,
                p.a10h[(t + 1) & 3], p.a10l[(t + 1) & 3], K1P_, NNIN_,
                p.a20h[t & 3], p.a20l[t & 3], K2P_, 0, 0);
        }
    } else if (blk < 512) {                // B0(t=s-1)
        int t = s - 1;
        if (t >= 0 && t < T_) {
            int b2 = blk - 256;
            gemm_lstm_tile(tid, b2 & 31, b2 >> 5, smem,
                p.a20h[t & 3], p.a20l[t & 3], K2P_, p.w20, K2P_ / 32,
                p.bih1, p.bhh1, p.c01,
                p.a20h[(t + 1) & 3], p.a20l[(t + 1) & 3], K2P_, H_,
                p.a11h[t & 3], p.a11l[t & 3], K1P_, 0, 1);
        }
    } else if (blk < 768) {                // A1(t=s-4)
        int t = s - 4;
        if (t >= 0 && t < T_) {
            int b2 = blk - 512;
            gemm_lstm_tile(tid, b2 & 31, b2 >> 5, smem,
                p.a11h[t & 3], p.a11l[t & 3], K1P_, p.w11, K1P_ / 32,
                p.bih0 + 2048, p.bhh0 + 2048, p.c10,
                p.a11h[(t + 1) & 3], p.a11l[(t + 1) & 3], K1P_, NNIN_,
                p.a21h[t & 3], p.a21l[t & 3], K2P_, 0, 0);
        }
    } else if (blk < 1024) {               // B1(t=s-5)
        int t = s - 5;
        if (t >= 0 && t < T_) {
            int b2 = blk - 768;
            gemm_lstm_tile(tid, b2 & 31, b2 >> 5, smem,
                p.a21h[t & 3], p.a21l[t & 3], K2P_, p.w21, K2P_ / 32,
                p.bih1 + 2048, p.bhh1 + 2048, p.c11,
                p.a21h[(t + 1) & 3], p.a21l[(t + 1) & 3], K2P_, H_,
                p.yh[t & 3], p.yl[t & 3], KOP_, 0, 1);
        }
    } else if (blk < 1152) {               // M0(t=s-3)
        int t = s - 3;
        if (t >= 0 && t < T_) {
            mem_group(blk - 1024, tid, smem, p.S0[t & 1],
                p.mem0, p.link0, p.prec0, p.rw0, p.ww0, p.us0,
                p.a11h[t & 3], p.a11l[t & 3], K1P_);
        }
    } else if (blk < 1280) {               // M1(t=s-7)
        int t = s - 7;
        if (t >= 0 && t < T_) {
            mem_group(blk - 1152, tid, smem, p.S1[t & 1],
                p.mem1, p.link1, p.prec1, p.rw1, p.ww1, p.us1,
                p.yh[t & 3], p.yl[t & 3], KOP_);
        }
    } else if (blk < 1536) {               // Y(t=s-8)
        int t = s - 8;
        if (t >= 0 && t < T_) {
            int tile = blk - 1280;
            gemm_plain_tile(tid, tile & 31, tile >> 5, smem,
                p.yh[t & 3], p.yl[t & 3], KOP_, p.wo, KOP_, KOP_ / 32,
                p.bout, p.out + (size_t)t * IN_, T_ * IN_);
        }
    } else if (blk < 1624) {               // IF0(t=s-2)
        int t = s - 2;
        if (t >= 0 && t < T_) {
            int b2 = blk - 1536;
            gemm_iface_tile(tid, b2 % 11, b2 / 11, smem,
                p.a11h[t & 3], p.a11l[t & 3], K1P_,
                p.wif0h, p.wif0l, p.bif0, p.S0[t & 1]);
        }
    } else if (blk < 1712) {               // IF1(t=s-6)
        int t = s - 6;
        if (t >= 0 && t < T_) {
            int b2 = blk - 1624;
            gemm_iface_tile(tid, b2 % 11, b2 / 11, smem,
                p.yh[t & 3], p.yl[t & 3], KOP_,
                p.wif1h, p.wif1l, p.bif1, p.S1[t & 1]);
        }
    } else {                               // x(s+1) convert
        int tn = s + 1;
        if (tn < T_) {
            for (int i = (blk - 1712) * 256 + tid; i < B_ * IN_; i += 32 * 256) {
                int b = i >> 9, j = i & 511;
                float v = p.x[((size_t)b * T_ + tn) * IN_ + j];
                split2(v, &p.a10h[tn & 3][(size_t)b * K1P_ + j],
                          &p.a10l[tn & 3][(size_t)b * K1P_ + j]);
            }
        }
    }
}

// ---------------------------------------------------------------------------
// Setup kernels
// ---------------------------------------------------------------------------
struct ConvArgs { const float* s1; const float* s2; __bf16* dst; int K1, K2, Kd; };
struct ConvArgs4 { ConvArgs a[4]; };

__global__ __launch_bounds__(256) void conv_lstm(ConvArgs4 ca)
{
    ConvArgs c = ca.a[blockIdx.z];
    int k = blockIdx.x * 256 + threadIdx.x;
    if (k >= c.Kd) return;
    int n = blockIdx.y;
    float v = 0.f;
    if (k < c.K1) v = c.s1[(size_t)n * c.K1 + k];
    else if (k < c.K1 + c.K2) v = c.s2[(size_t)n * c.K2 + (k - c.K1)];
    c.dst[(size_t)n * c.Kd + k] = (__bf16)v;
}

__global__ __launch_bounds__(256) void conv_hi(
    const float* __restrict__ s1, int K1, const float* __restrict__ s2, int K2,
    int Nsrc, __bf16* __restrict__ hi, int Kd)
{
    int k = blockIdx.x * 256 + threadIdx.x;
    int n = blockIdx.y;
    if (k >= Kd) return;
    float v = 0.f;
    if (n < Nsrc) {
        if (k < K1) v = s1[(size_t)n * K1 + k];
        else if (k < K1 + K2) v = s2[(size_t)n * K2 + (k - K1)];
    }
    hi[(size_t)n * Kd + k] = (__bf16)v;
}

__global__ __launch_bounds__(256) void conv_hl(
    const float* __restrict__ src, int Nsrc, int K,
    __bf16* __restrict__ hi, __bf16* __restrict__ lo)
{
    int k = blockIdx.x * 256 + threadIdx.x;
    int n = blockIdx.y;
    if (k >= K) return;
    float v = (n < Nsrc) ? src[(size_t)n * K + k] : 0.f;
    split2(v, &hi[(size_t)n * K + k], &lo[(size_t)n * K + k]);
}

__global__ __launch_bounds__(256) void build_inp(const float* __restrict__ x,
                                                 __bf16* __restrict__ a1h,
                                                 __bf16* __restrict__ a1l)
{
    int idx = blockIdx.x * 256 + threadIdx.x;
    if (idx >= B_ * IN_) return;
    int b = idx >> 9, j = idx & 511;
    float v = x[(size_t)b * T_ * IN_ + j];
    split2(v, &a1h[b * K1P_ + j], &a1l[b * K1P_ + j]);
}

// ---------------------------------------------------------------------------
extern "C" void kernel_launch(void* const* d_in, const int* in_sizes, int n_in,
                              void* d_out, int out_size, void* d_ws, size_t ws_size,
                              hipStream_t stream)
{
    const float* x       = (const float*)d_in[0];
    const float* W_ih0   = (const float*)d_in[1];
    const float* W_hh0   = (const float*)d_in[2];
    const float* b_ih0   = (const float*)d_in[3];
    const float* b_hh0   = (const float*)d_in[4];
    const float* W_ih1   = (const float*)d_in[5];
    const float* W_hh1   = (const float*)d_in[6];
    const float* b_ih1   = (const float*)d_in[7];
    const float* b_hh1   = (const float*)d_in[8];
    const float* W_iface = (const float*)d_in[9];
    const float* b_iface = (const float*)d_in[10];
    const float* W_out   = (const float*)d_in[11];
    const float* b_out   = (const float*)d_in[12];

    P p;
    p.x = x;
    p.bih0 = b_ih0; p.bhh0 = b_hh0; p.bih1 = b_ih1; p.bhh1 = b_hh1;
    p.bif0 = b_iface; p.bif1 = b_iface + IFACE_;
    p.bout = b_out;
    p.out = (float*)d_out;

    char* ptr = (char*)d_ws;
    auto alloc = [&](size_t bytes) { char* r = ptr; ptr += (bytes + 255) & ~(size_t)255; return r; };

    // ---- zero zone (memset each call) ----
    char* zstart = ptr;
    for (int q = 0; q < 4; ++q) { p.a10h[q] = (__bf16*)alloc(B_ * K1P_ * 2); p.a10l[q] = (__bf16*)alloc(B_ * K1P_ * 2); }
    for (int q = 0; q < 4; ++q) { p.a11h[q] = (__bf16*)alloc(B_ * K1P_ * 2); p.a11l[q] = (__bf16*)alloc(B_ * K1P_ * 2); }
    for (int q = 0; q < 4; ++q) { p.a20h[q] = (__bf16*)alloc(B_ * K2P_ * 2); p.a20l[q] = (__bf16*)alloc(B_ * K2P_ * 2); }
    for (int q = 0; q < 4; ++q) { p.a21h[q] = (__bf16*)alloc(B_ * K2P_ * 2); p.a21l[q] = (__bf16*)alloc(B_ * K2P_ * 2); }
    for (int q = 0; q < 4; ++q) { p.yh[q]  = (__bf16*)alloc(B_ * KOP_ * 2);  p.yl[q]  = (__bf16*)alloc(B_ * KOP_ * 2); }
    p.c00 = (float*)alloc((size_t)B_ * H_ * 4);
    p.c01 = (float*)alloc((size_t)B_ * H_ * 4);
    p.c10 = (float*)alloc((size_t)B_ * H_ * 4);
    p.c11 = (float*)alloc((size_t)B_ * H_ * 4);
    p.mem0  = (float*)alloc((size_t)B_ * M_ * WC_ * 4);
    p.link0 = (float*)alloc((size_t)B_ * M_ * M_ * 4);
    p.prec0 = (float*)alloc((size_t)B_ * M_ * 4);
    p.rw0   = (float*)alloc((size_t)B_ * R_ * M_ * 4);
    p.ww0   = (float*)alloc((size_t)B_ * M_ * 4);
    p.us0   = (float*)alloc((size_t)B_ * M_ * 4);
    p.mem1  = (float*)alloc((size_t)B_ * M_ * WC_ * 4);
    p.link1 = (float*)alloc((size_t)B_ * M_ * M_ * 4);
    p.prec1 = (float*)alloc((size_t)B_ * M_ * 4);
    p.rw1   = (float*)alloc((size_t)B_ * R_ * M_ * 4);
    p.ww1   = (float*)alloc((size_t)B_ * M_ * 4);
    p.us1   = (float*)alloc((size_t)B_ * M_ * 4);
    size_t zbytes = (size_t)(ptr - zstart);

    // ---- weights (rewritten every call) ----
    p.w10 = (__bf16*)alloc(2048ull * K1P_ * 2);
    p.w11 = (__bf16*)alloc(2048ull * K1P_ * 2);
    p.w20 = (__bf16*)alloc(2048ull * K2P_ * 2);
    p.w21 = (__bf16*)alloc(2048ull * K2P_ * 2);
    p.wo  = (__bf16*)alloc(512ull * KOP_ * 2);
    p.wif0h = (__bf16*)alloc((size_t)IFP_ * 512 * 2);
    p.wif0l = (__bf16*)alloc((size_t)IFP_ * 512 * 2);
    p.wif1h = (__bf16*)alloc((size_t)IFP_ * 512 * 2);
    p.wif1l = (__bf16*)alloc((size_t)IFP_ * 512 * 2);
    for (int q = 0; q < 2; ++q) p.S0[q] = (float*)alloc((size_t)B_ * IFP_ * 4);
    for (int q = 0; q < 2; ++q) p.S1[q] = (float*)alloc((size_t)B_ * IFP_ * 4);

    hipMemsetAsync(zstart, 0, zbytes, stream);

    ConvArgs4 ca;
    ca.a[0] = { W_ih0,                 W_hh0,                 p.w10, NNIN_, H_, K1P_ };
    ca.a[1] = { W_ih0 + 2048ull*NNIN_, W_hh0 + 2048ull*H_,    p.w11, NNIN_, H_, K1P_ };
    ca.a[2] = { W_ih1,                 W_hh1,                 p.w20, H_,    H_, K2P_ };
    ca.a[3] = { W_ih1 + 2048ull*H_,    W_hh1 + 2048ull*H_,    p.w21, H_,    H_, K2P_ };
    conv_lstm<<<dim3((K1P_ + 255) / 256, 2048, 4), 256, 0, stream>>>(ca);

    conv_hi<<<dim3((KOP_ + 255) / 256, 512), 256, 0, stream>>>(
        W_out, NNIN_, nullptr, 0, 512, p.wo, KOP_);
    conv_hl<<<dim3(2, IFP_), 256, 0, stream>>>(
        W_iface, IFACE_, 512, p.wif0h, p.wif0l);
    conv_hl<<<dim3(2, IFP_), 256, 0, stream>>>(
        W_iface + (size_t)IFACE_ * 512, IFACE_, 512, p.wif1h, p.wif1l);
    build_inp<<<(B_ * IN_ + 255) / 256, 256, 0, stream>>>(x, p.a10h[0], p.a10l[0]);

    // 40 pipeline slots cover t=0..31 for all 9 stages
    for (int s = 0; s < T_ + 8; ++s) {
        slot_kernel<<<1744, 256, 0, stream>>>(p, s);
    }
}